// Round 10
// baseline (54.002 us; speedup 1.0000x reference)
//
#include <hip/hip_runtime.h>
#include <math.h>

#define NJ  16
#define BLK 256

// 1 thread per element, zero cross-lane ops, cheap trig, immediate stores.
// Minimum-total-VALU structure: ~1200 VALU/element vs the 4-lane scan's ~3700.
__global__ __launch_bounds__(BLK) void poe_fwd(
    const float* __restrict__ q,        // B x 16
    const float* __restrict__ twist,    // 16 x 6 (uniform)
    const float* __restrict__ init_p,   // 3
    const float* __restrict__ init_rpy, // 3
    float* __restrict__ outT,           // B x 16
    float* __restrict__ outTw,          // B x 96
    int nb)
{
    const int b = blockIdx.x * BLK + threadIdx.x;
    if (b >= nb) return;

    // ---- all 16 joint angles (4 coalesced float4 loads) ----
    float qv[NJ];
    {
        const float4* q4 = reinterpret_cast<const float4*>(q + (size_t)b * NJ);
        #pragma unroll
        for (int i = 0; i < NJ / 4; ++i) {
            float4 t = q4[i];
            qv[4*i+0] = t.x; qv[4*i+1] = t.y; qv[4*i+2] = t.z; qv[4*i+3] = t.w;
        }
    }

    // ---- running pose T = (R | p) ----
    float R00=1.f, R01=0.f, R02=0.f;
    float R10=0.f, R11=1.f, R12=0.f;
    float R20=0.f, R21=0.f, R22=1.f;
    float p0=0.f, p1=0.f, p2=0.f;

    float* twb = outTw + (size_t)b * (NJ * 6);

    #pragma unroll
    for (int j = 0; j < NJ; ++j) {
        // uniform twist row (L1-resident, compile-time offsets)
        const float w0 = twist[j*6+0], w1 = twist[j*6+1], w2 = twist[j*6+2];
        const float v0 = twist[j*6+3], v1 = twist[j*6+4], v2 = twist[j*6+5];

        // ---- tw_local from CURRENT pose; store immediately (16B + 8B) ----
        {
            float u0 = v0 - (p1*w2 - p2*w1);
            float u1 = v1 - (p2*w0 - p0*w2);
            float u2 = v2 - (p0*w1 - p1*w0);
            float wl0 = R00*w0 + R10*w1 + R20*w2;
            float wl1 = R01*w0 + R11*w1 + R21*w2;
            float wl2 = R02*w0 + R12*w1 + R22*w2;
            float vl0 = R00*u0 + R10*u1 + R20*u2;
            float vl1 = R01*u0 + R11*u1 + R21*u2;
            float vl2 = R02*u0 + R12*u1 + R22*u2;
            *reinterpret_cast<float4*>(twb + 6*j)     = make_float4(wl0, wl1, wl2, vl0);
            *reinterpret_cast<float2*>(twb + 6*j + 4) = make_float2(vl1, vl2);
        }

        // ---- joint exponential A_j (cheap trig) ----
        float ww    = w0*w0 + w1*w1 + w2*w2;
        float theta = sqrtf(ww) + 1e-12f;
        float inv   = __builtin_amdgcn_rcpf(theta);
        float wn0 = w0*inv, wn1 = w1*inv, wn2 = w2*inv;
        float vn0 = v0*inv, vn1 = v1*inv, vn2 = v2*inv;
        float qt  = qv[j] * theta;
        float s   = __sinf(qt);
        float cth = __cosf(qt);
        float c   = 1.0f - cth;
        float ts  = qt - s;

        float a00 = cth + c*wn0*wn0;
        float a01 = c*wn0*wn1 - s*wn2;
        float a02 = c*wn0*wn2 + s*wn1;
        float a10 = c*wn1*wn0 + s*wn2;
        float a11 = cth + c*wn1*wn1;
        float a12 = c*wn1*wn2 - s*wn0;
        float a20 = c*wn2*wn0 - s*wn1;
        float a21 = c*wn2*wn1 + s*wn0;
        float a22 = cth + c*wn2*wn2;

        float cx0 = wn1*vn2 - wn2*vn1;
        float cx1 = wn2*vn0 - wn0*vn2;
        float cx2 = wn0*vn1 - wn1*vn0;
        float d   = wn0*vn0 + wn1*vn1 + wn2*vn2;
        float td  = ts * d;
        float pj0 = s*vn0 + c*cx0 + td*wn0;
        float pj1 = s*vn1 + c*cx1 + td*wn1;
        float pj2 = s*vn2 + c*cx2 + td*wn2;

        // ---- T = T @ A_j ----
        float n00 = R00*a00 + R01*a10 + R02*a20;
        float n01 = R00*a01 + R01*a11 + R02*a21;
        float n02 = R00*a02 + R01*a12 + R02*a22;
        float n10 = R10*a00 + R11*a10 + R12*a20;
        float n11 = R10*a01 + R11*a11 + R12*a21;
        float n12 = R10*a02 + R11*a12 + R12*a22;
        float n20 = R20*a00 + R21*a10 + R22*a20;
        float n21 = R20*a01 + R21*a11 + R22*a21;
        float n22 = R20*a02 + R21*a12 + R22*a22;
        float np0 = R00*pj0 + R01*pj1 + R02*pj2 + p0;
        float np1 = R10*pj0 + R11*pj1 + R12*pj2 + p1;
        float np2 = R20*pj0 + R21*pj1 + R22*pj2 + p2;
        R00=n00; R01=n01; R02=n02;
        R10=n10; R11=n11; R12=n12;
        R20=n20; R21=n21; R22=n22;
        p0=np0; p1=np1; p2=np2;
    }

    // ---- T_init = pr2t(init_p, init_rpy); final = T @ T_init ----
    float rr = init_rpy[0], pt = init_rpy[1], yw = init_rpy[2];
    float sr = __sinf(rr), cr = __cosf(rr);
    float sp = __sinf(pt), cp = __cosf(pt);
    float sy = __sinf(yw), cy = __cosf(yw);
    float i00 = cy*cp, i01 = cy*sp*sr - sy*cr, i02 = cy*sp*cr + sy*sr;
    float i10 = sy*cp, i11 = sy*sp*sr + cy*cr, i12 = sy*sp*cr - cy*sr;
    float i20 = -sp,   i21 = cp*sr,            i22 = cp*cr;
    float ip0 = init_p[0], ip1 = init_p[1], ip2 = init_p[2];

    float f00 = R00*i00 + R01*i10 + R02*i20;
    float f01 = R00*i01 + R01*i11 + R02*i21;
    float f02 = R00*i02 + R01*i12 + R02*i22;
    float f10 = R10*i00 + R11*i10 + R12*i20;
    float f11 = R10*i01 + R11*i11 + R12*i21;
    float f12 = R10*i02 + R11*i12 + R12*i22;
    float f20 = R20*i00 + R21*i10 + R22*i20;
    float f21 = R20*i01 + R21*i11 + R22*i21;
    float f22 = R20*i02 + R21*i12 + R22*i22;
    float fp0 = R00*ip0 + R01*ip1 + R02*ip2 + p0;
    float fp1 = R10*ip0 + R11*ip1 + R12*ip2 + p1;
    float fp2 = R20*ip0 + R21*ip1 + R22*ip2 + p2;

    float4* o4 = reinterpret_cast<float4*>(outT + (size_t)b * 16);
    o4[0] = make_float4(f00, f01, f02, fp0);
    o4[1] = make_float4(f10, f11, f12, fp1);
    o4[2] = make_float4(f20, f21, f22, fp2);
    o4[3] = make_float4(0.f, 0.f, 0.f, 1.f);
}

extern "C" void kernel_launch(void* const* d_in, const int* in_sizes, int n_in,
                              void* d_out, int out_size, void* d_ws, size_t ws_size,
                              hipStream_t stream) {
    const float* q        = (const float*)d_in[0];
    const float* twist    = (const float*)d_in[1];
    const float* init_p   = (const float*)d_in[2];
    const float* init_rpy = (const float*)d_in[3];

    int nb = in_sizes[0] / NJ;   // B
    float* outT  = (float*)d_out;                  // B x 16 (4x4 matrices)
    float* outTw = outT + (size_t)nb * 16;         // B x 96 (Twistls)

    int blocks = (nb + BLK - 1) / BLK;
    poe_fwd<<<blocks, BLK, 0, stream>>>(q, twist, init_p, init_rpy, outT, outTw, nb);
}